// Round 5
// baseline (4863.500 us; speedup 1.0000x reference)
//
#include <hip/hip_runtime.h>
#include <hip/hip_bf16.h>
#include <math.h>

#define B_   2
#define S_   2048
#define D_   512
#define H_   8
#define DH_  64
#define NL_  4
#define MLP_ 2048
#define V_   32000
#define BS_  (B_ * S_)
#define WINH_ 256   // WIN/2

typedef unsigned short u16;
using short8 = __attribute__((ext_vector_type(8))) short;
using u16x4  = __attribute__((ext_vector_type(4))) unsigned short;
using f32x4  = __attribute__((ext_vector_type(4))) float;

// ---------------------------------------------------------------------------
// fp32 -> (hi, lo) bf16 split, RNE both steps; lo residual is exact.
// a ~= hi + lo with |a - hi - lo| <~ 2^-17 |a|  (3-term MFMA drops al*bl).
// ---------------------------------------------------------------------------
__device__ __forceinline__ void split1(float f, u16& h, u16& l) {
    union { float f; unsigned u; } c; c.f = f;
    unsigned hb = (c.u + 0x7FFFu + ((c.u >> 16) & 1u)) & 0xFFFF0000u;
    h = (u16)(hb >> 16);
    union { unsigned u; float f; } hc; hc.u = hb;
    float r = f - hc.f;
    union { float f; unsigned u; } rc; rc.f = r;
    l = (u16)((rc.u + 0x7FFFu + ((rc.u >> 16) & 1u)) >> 16);
}

// ---------------------------------------------------------------------------
// Embedding + sinusoidal PE.  ids = shift_right(inputs); x stays fp32.
// ---------------------------------------------------------------------------
__global__ __launch_bounds__(256) void embed_kernel(
    const int* __restrict__ inputs, const float* __restrict__ embed,
    float* __restrict__ x)
{
    int idx = blockIdx.x * 256 + threadIdx.x;     // over BS_*D_ = 2^21 exactly
    int d = idx & (D_ - 1);
    int s = (idx >> 9) & (S_ - 1);
    int b = idx >> 20;
    int id = (s == 0) ? 0 : inputs[b * S_ + s - 1];
    float freq = expf(-(float)(d & ~1) * (9.210340371976184f / (float)D_));
    float ang = (float)s * freq;
    float pe = (d & 1) ? cosf(ang) : sinf(ang);
    x[idx] = embed[(size_t)id * D_ + d] + pe;
}

// ---------------------------------------------------------------------------
// Weight transpose + split: w[K][N] fp32 -> th/tl[N][K] bf16 (per layer z).
// 32x32 LDS tile; both global sides coalesced.
// ---------------------------------------------------------------------------
__global__ __launch_bounds__(256) void tsplit_kernel(
    const float* __restrict__ w, u16* __restrict__ th, u16* __restrict__ tl,
    int K, int N)
{
    __shared__ float tile[32][33];
    int z = blockIdx.z;
    const float* wp = w + (size_t)z * K * N;
    u16* thp = th + (size_t)z * K * N;
    u16* tlp = tl + (size_t)z * K * N;
    int k0 = blockIdx.y * 32, n0 = blockIdx.x * 32;
    int tx = threadIdx.x & 31, ty = threadIdx.x >> 5;   // ty 0..7
#pragma unroll
    for (int i = 0; i < 4; i++)
        tile[ty + i * 8][tx] = wp[(size_t)(k0 + ty + i * 8) * N + n0 + tx];
    __syncthreads();
#pragma unroll
    for (int i = 0; i < 4; i++) {
        int n = n0 + ty + i * 8, k = k0 + tx;
        u16 h, l; split1(tile[tx][ty + i * 8], h, l);
        thp[(size_t)n * K + k] = h;
        tlp[(size_t)n * K + k] = l;
    }
}

// ---------------------------------------------------------------------------
// LayerNorm: one wave per 512-elem row; emits hi/lo bf16 (GEMM A-operand).
// ---------------------------------------------------------------------------
__global__ __launch_bounds__(256) void ln_kernel(
    const float* __restrict__ x, const float* __restrict__ sc,
    const float* __restrict__ bi, u16* __restrict__ yh, u16* __restrict__ yl)
{
    int wave = threadIdx.x >> 6, lane = threadIdx.x & 63;
    int row = blockIdx.x * 4 + wave;
    const float4* xr = (const float4*)(x + (size_t)row * D_);
    float4 a0 = xr[lane];
    float4 a1 = xr[lane + 64];
    float sum = a0.x + a0.y + a0.z + a0.w + a1.x + a1.y + a1.z + a1.w;
#pragma unroll
    for (int off = 32; off; off >>= 1) sum += __shfl_xor(sum, off);
    float mu = sum * (1.0f / (float)D_);
    float c0x = a0.x - mu, c0y = a0.y - mu, c0z = a0.z - mu, c0w = a0.w - mu;
    float c1x = a1.x - mu, c1y = a1.y - mu, c1z = a1.z - mu, c1w = a1.w - mu;
    float vs = c0x*c0x + c0y*c0y + c0z*c0z + c0w*c0w
             + c1x*c1x + c1y*c1y + c1z*c1z + c1w*c1w;
#pragma unroll
    for (int off = 32; off; off >>= 1) vs += __shfl_xor(vs, off);
    float r = 1.0f / sqrtf(vs * (1.0f / (float)D_) + 1e-6f);
    const float4* s4 = (const float4*)sc;
    const float4* b4 = (const float4*)bi;
    float4 s0 = s4[lane], s1 = s4[lane + 64];
    float4 bb0 = b4[lane], bb1 = b4[lane + 64];
    float o[8];
    o[0] = c0x * r * s0.x + bb0.x;  o[1] = c0y * r * s0.y + bb0.y;
    o[2] = c0z * r * s0.z + bb0.z;  o[3] = c0w * r * s0.w + bb0.w;
    o[4] = c1x * r * s1.x + bb1.x;  o[5] = c1y * r * s1.y + bb1.y;
    o[6] = c1z * r * s1.z + bb1.z;  o[7] = c1w * r * s1.w + bb1.w;
    u16x4 h0, l0, h1, l1;
#pragma unroll
    for (int j = 0; j < 4; j++) { u16 h, l; split1(o[j], h, l); h0[j] = h; l0[j] = l; }
#pragma unroll
    for (int j = 0; j < 4; j++) { u16 h, l; split1(o[4 + j], h, l); h1[j] = h; l1[j] = l; }
    u16x4* yh4 = (u16x4*)(yh + (size_t)row * D_);
    u16x4* yl4 = (u16x4*)(yl + (size_t)row * D_);
    yh4[lane] = h0;  yh4[lane + 64] = h1;
    yl4[lane] = l0;  yl4[lane + 64] = l1;
}

// ---------------------------------------------------------------------------
// Sliding-window causal attention. One wave per (b, h, q); lane = dim.
// Reads fp32 q/k/v; emits hi/lo bf16 (feeds WO GEMM as A).
// ---------------------------------------------------------------------------
__global__ __launch_bounds__(256) void attn_kernel(
    const float* __restrict__ q, const float* __restrict__ k,
    const float* __restrict__ v, const int* __restrict__ inputs,
    u16* __restrict__ atth, u16* __restrict__ attl)
{
    int wv = threadIdx.x >> 6, lane = threadIdx.x & 63;
    int w = blockIdx.x * 4 + wv;          // [0, B_*H_*S_)
    int qpos = w & (S_ - 1);
    int h = (w >> 11) & (H_ - 1);
    int b = w >> 14;
    int rowbase = b * S_;
    int hcol = h * DH_;
    bool padq = inputs[rowbase + qpos] > 0;
    float o = 0.0f;
    if (!padq) {
        float acc = 0.0f;
        for (int kk = 0; kk < S_; kk++)
            acc += v[(size_t)(rowbase + kk) * D_ + hcol + lane];
        o = acc * (1.0f / (float)S_);
    } else {
        float qv = q[(size_t)(rowbase + qpos) * D_ + hcol + lane] * 0.125f;
        float m = -1e30f, l = 0.0f;
        int lo = qpos - WINH_; if (lo < 0) lo = 0;
        for (int kk = lo; kk <= qpos; kk++) {
            if (inputs[rowbase + kk] <= 0) continue;   // exact: exp underflows
            float sc = qv * k[(size_t)(rowbase + kk) * D_ + hcol + lane];
#pragma unroll
            for (int off = 32; off; off >>= 1) sc += __shfl_xor(sc, off);
            if (sc > m) {
                float c = expf(m - sc);
                o *= c; l *= c; m = sc;
            }
            float p = expf(sc - m);
            l += p;
            o += p * v[(size_t)(rowbase + kk) * D_ + hcol + lane];
        }
        o /= l;
    }
    u16 hh, ll; split1(o, hh, ll);
    size_t oi = (size_t)(rowbase + qpos) * D_ + hcol + lane;
    atth[oi] = hh;
    attl[oi] = ll;
}

// ---------------------------------------------------------------------------
// Split-bf16 MFMA GEMM, pre-split operands.  C = A @ B (+epilogue).
// A given as Ah/Al bf16 [M][K].  B: BSPLIT ? Bth/Btl bf16 [N][K] (transposed)
//                                          : Bf fp32 [K][N] (split on the fly).
// 3 MFMAs (ah*bh + ah*bl + al*bh) per fragment pair; fp32-level accuracy.
// MFMA 16x16x32 bf16.  C/D map (m89-verified): col=lane&15, row=(lane>>4)*4+r.
// A/B map (standard gfx950): row/col=lane&15, k=(lane>>4)*8+j.
// LDS k-contiguous rows, padded stride 40 shorts (80 B).
// MODE 0: C=acc  1: C+=acc  2: Ch/Cl=split(gelu(acc+bias))
// MODE 3: C+=acc+bias  4: C=acc+bias
// ---------------------------------------------------------------------------
__device__ __forceinline__ float gelu_f(float v) {
    float u = v + 0.044715f * v * v * v;
    return 0.5f * v * (1.0f + tanhf(0.7978845608028654f * u));
}

template<int MODE, int BM, int BN, int FM, int FN, bool BSPLIT>
__device__ __forceinline__ void mgemm_body(
    const u16* __restrict__ Ahg, const u16* __restrict__ Alg,
    const u16* __restrict__ Bth, const u16* __restrict__ Btl,
    const float* __restrict__ Bf, const float* __restrict__ bias,
    float* __restrict__ C, u16* __restrict__ Ch, u16* __restrict__ Cl,
    int M, int N, int K)
{
    constexpr int BK = 32;
    constexpr int SP = 40;                  // LDS k-stride (shorts): 80 B
    constexpr int WN = BN / (16 * FN);
    constexpr int WM = BM / (16 * FM);
    static_assert(WM * WN == 4, "4 waves");
    __shared__ __align__(16) short Ah[BM][SP], Al[BM][SP];
    __shared__ __align__(16) short Bh[BN][SP], Bl[BN][SP];

    const int tid  = threadIdx.x;
    const int lane = tid & 63, wid = tid >> 6;
    const int wm = wid / WN, wn = wid % WN;
    const int m0 = blockIdx.y * BM, n0 = blockIdx.x * BN;

    f32x4 acc[FM][FN] = {};

    const int srow = tid >> 2, sq = tid & 3;    // copy task: 4 short8 per row

    for (int k0 = 0; k0 < K; k0 += BK) {
        // ---- stage A: pure short8 copy (no conversion)
#pragma unroll
        for (int t = 0; t < BM / 64; t++) {
            int row = srow + t * 64;
            size_t go = (size_t)(m0 + row) * K + k0 + sq * 8;
            *(short8*)&Ah[row][sq * 8] = *(const short8*)(Ahg + go);
            *(short8*)&Al[row][sq * 8] = *(const short8*)(Alg + go);
        }
        if constexpr (BSPLIT) {
            // ---- stage B: transposed pre-split weights, same pure copy
#pragma unroll
            for (int t = 0; t < BN / 64; t++) {
                int row = srow + t * 64;
                size_t go = (size_t)(n0 + row) * K + k0 + sq * 8;
                *(short8*)&Bh[row][sq * 8] = *(const short8*)(Bth + go);
                *(short8*)&Bl[row][sq * 8] = *(const short8*)(Btl + go);
            }
        } else {
            // ---- stage B: fp32 [K][N], split on the fly (logits only)
#pragma unroll
            for (int t = 0; t < BN / 32; t++) {
                int f   = tid + t * 256;
                int col = f & (BN - 1);
                int kq  = f / BN;                 // 0..7
                const float* bp = Bf + (size_t)(k0 + kq * 4) * N + n0 + col;
                float b0 = bp[0];
                float b1 = bp[(size_t)N];
                float b2 = bp[2 * (size_t)N];
                float b3 = bp[3 * (size_t)N];
                u16x4 h, l; u16 hh, ll;
                split1(b0, hh, ll); h[0] = hh; l[0] = ll;
                split1(b1, hh, ll); h[1] = hh; l[1] = ll;
                split1(b2, hh, ll); h[2] = hh; l[2] = ll;
                split1(b3, hh, ll); h[3] = hh; l[3] = ll;
                *(u16x4*)&Bh[col][kq * 4] = h;
                *(u16x4*)&Bl[col][kq * 4] = l;
            }
        }
        __syncthreads();

        // ---- fragments + MFMA
        const int fr = lane & 15, fh = lane >> 4;
        short8 ah[FM], al[FM];
#pragma unroll
        for (int i = 0; i < FM; i++) {
            int r = wm * FM * 16 + i * 16 + fr;
            ah[i] = *(const short8*)&Ah[r][fh * 8];
            al[i] = *(const short8*)&Al[r][fh * 8];
        }
#pragma unroll
        for (int j = 0; j < FN; j++) {
            int c = wn * FN * 16 + j * 16 + fr;
            short8 bh = *(const short8*)&Bh[c][fh * 8];
            short8 bl = *(const short8*)&Bl[c][fh * 8];
#pragma unroll
            for (int i = 0; i < FM; i++) {
                acc[i][j] = __builtin_amdgcn_mfma_f32_16x16x32_bf16(ah[i], bh, acc[i][j], 0, 0, 0);
                acc[i][j] = __builtin_amdgcn_mfma_f32_16x16x32_bf16(ah[i], bl, acc[i][j], 0, 0, 0);
                acc[i][j] = __builtin_amdgcn_mfma_f32_16x16x32_bf16(al[i], bh, acc[i][j], 0, 0, 0);
            }
        }
        __syncthreads();
    }

    // ---- epilogue: D[row=(lane>>4)*4+r][col=lane&15] per fragment
    const int fr = lane & 15, fq = lane >> 4;
#pragma unroll
    for (int i = 0; i < FM; i++) {
#pragma unroll
        for (int j = 0; j < FN; j++) {
            int col = n0 + wn * FN * 16 + j * 16 + fr;
            float bv = 0.0f;
            if constexpr (MODE >= 2) bv = bias[col];
#pragma unroll
            for (int r = 0; r < 4; r++) {
                int row = m0 + wm * FM * 16 + i * 16 + fq * 4 + r;
                size_t ci = (size_t)row * N + col;
                float val = acc[i][j][r];
                if constexpr (MODE == 0) C[ci] = val;
                if constexpr (MODE == 1) C[ci] += val;
                if constexpr (MODE == 2) {
                    u16 hh, ll; split1(gelu_f(val + bv), hh, ll);
                    Ch[ci] = hh; Cl[ci] = ll;
                }
                if constexpr (MODE == 3) C[ci] += val + bv;
                if constexpr (MODE == 4) C[ci] = val + bv;
            }
        }
    }
}

template<int MODE, int BM, int BN, int FM, int FN, bool BSPLIT>
__global__ __launch_bounds__(256) void mgemm_kernel(
    const u16* __restrict__ Ahg, const u16* __restrict__ Alg,
    const u16* __restrict__ Bth, const u16* __restrict__ Btl,
    const float* __restrict__ Bf, const float* __restrict__ bias,
    float* __restrict__ C, u16* __restrict__ Ch, u16* __restrict__ Cl,
    int M, int N, int K)
{
    mgemm_body<MODE, BM, BN, FM, FN, BSPLIT>(Ahg, Alg, Bth, Btl, Bf, bias,
                                             C, Ch, Cl, M, N, K);
}

// Fused Q/K/V projection: blockIdx.z selects weight/output (768 blocks).
__global__ __launch_bounds__(256) void qkv_kernel(
    const u16* __restrict__ yh, const u16* __restrict__ yl,
    const u16* __restrict__ wqh, const u16* __restrict__ wql,
    const u16* __restrict__ wkh, const u16* __restrict__ wkl,
    const u16* __restrict__ wvh, const u16* __restrict__ wvl,
    float* __restrict__ qb, float* __restrict__ kb, float* __restrict__ vb)
{
    int z = blockIdx.z;
    const u16* bh = (z == 0) ? wqh : (z == 1) ? wkh : wvh;
    const u16* bl = (z == 0) ? wql : (z == 1) ? wkl : wvl;
    float*     C  = (z == 0) ? qb  : (z == 1) ? kb  : vb;
    mgemm_body<0, 128, 64, 4, 2, true>(yh, yl, bh, bl, nullptr, nullptr,
                                       C, nullptr, nullptr, BS_, D_, D_);
}

// ---------------------------------------------------------------------------
extern "C" void kernel_launch(void* const* d_in, const int* in_sizes, int n_in,
                              void* d_out, int out_size, void* d_ws, size_t ws_size,
                              hipStream_t stream)
{
    const int*   inputs = (const int*)  d_in[0];
    const float* embed  = (const float*)d_in[1];
    const float* wq     = (const float*)d_in[2];
    const float* wk     = (const float*)d_in[3];
    const float* wv     = (const float*)d_in[4];
    const float* wo     = (const float*)d_in[5];
    const float* ln1_s  = (const float*)d_in[6];
    const float* ln1_b  = (const float*)d_in[7];
    const float* ln2_s  = (const float*)d_in[8];
    const float* ln2_b  = (const float*)d_in[9];
    const float* w1     = (const float*)d_in[10];
    const float* b1     = (const float*)d_in[11];
    const float* w2     = (const float*)d_in[12];
    const float* b2     = (const float*)d_in[13];
    const float* lnf_s  = (const float*)d_in[14];
    const float* lnf_b  = (const float*)d_in[15];
    const float* w_out  = (const float*)d_in[16];
    const float* b_out  = (const float*)d_in[17];
    float* out = (float*)d_out;

    // --- d_ws (16 MB needed): x fp32 residual + yh/yl bf16 activation splits
    char* wsb = (char*)d_ws;
    float* x  = (float*)wsb;                               // 8 MB
    u16*   yh = (u16*)(wsb + (8u << 20));                  // 4 MB
    u16*   yl = (u16*)(wsb + (12u << 20));                 // 4 MB

    // --- d_out (524 MB) as scratch; everything dead before logits GEMM:
    //   [0,8)MB qb | [8,16) kb | [16,24) vb | [24,40) hbh | [40,56) hbl
    //   [56,104) transposed weight splits
    char* ob = (char*)d_out;
    float* qb  = (float*)(ob);
    float* kb  = (float*)(ob + (8u  << 20));
    float* vb  = (float*)(ob + (16u << 20));
    u16*   hbh = (u16*)  (ob + (24u << 20));
    u16*   hbl = (u16*)  (ob + (40u << 20));
    u16*   wqh = (u16*)  (ob + (56u << 20));
    u16*   wql = (u16*)  (ob + (58u << 20));
    u16*   wkh = (u16*)  (ob + (60u << 20));
    u16*   wkl = (u16*)  (ob + (62u << 20));
    u16*   wvh = (u16*)  (ob + (64u << 20));
    u16*   wvl = (u16*)  (ob + (66u << 20));
    u16*   woh = (u16*)  (ob + (68u << 20));
    u16*   wol = (u16*)  (ob + (70u << 20));
    u16*   w1h = (u16*)  (ob + (72u << 20));
    u16*   w1l = (u16*)  (ob + (80u << 20));
    u16*   w2h = (u16*)  (ob + (88u << 20));
    u16*   w2l = (u16*)  (ob + (96u << 20));

    // --- one-shot weight transpose+split (independent; ~20 us total)
    tsplit_kernel<<<dim3(D_/32,   D_/32, NL_), 256, 0, stream>>>(wq, wqh, wql, D_, D_);
    tsplit_kernel<<<dim3(D_/32,   D_/32, NL_), 256, 0, stream>>>(wk, wkh, wkl, D_, D_);
    tsplit_kernel<<<dim3(D_/32,   D_/32, NL_), 256, 0, stream>>>(wv, wvh, wvl, D_, D_);
    tsplit_kernel<<<dim3(D_/32,   D_/32, NL_), 256, 0, stream>>>(wo, woh, wol, D_, D_);
    tsplit_kernel<<<dim3(MLP_/32, D_/32, NL_), 256, 0, stream>>>(w1, w1h, w1l, D_, MLP_);
    tsplit_kernel<<<dim3(D_/32, MLP_/32, NL_), 256, 0, stream>>>(w2, w2h, w2l, MLP_, D_);

    embed_kernel<<<(BS_ * D_) / 256, 256, 0, stream>>>(inputs, embed, x);

    const size_t DD = (size_t)D_ * D_, DM = (size_t)D_ * MLP_;
    for (int l = 0; l < NL_; l++) {
        ln_kernel<<<BS_ / 4, 256, 0, stream>>>(x, ln1_s + l * D_, ln1_b + l * D_, yh, yl);
        qkv_kernel<<<dim3(D_ / 64, BS_ / 128, 3), 256, 0, stream>>>(
            yh, yl, wqh + l * DD, wql + l * DD, wkh + l * DD, wkl + l * DD,
            wvh + l * DD, wvl + l * DD, qb, kb, vb);
        attn_kernel<<<(B_ * H_ * S_) / 4, 256, 0, stream>>>(qb, kb, vb, inputs, yh, yl);
        mgemm_kernel<1, 64, 64, 2, 2, true><<<dim3(D_ / 64, BS_ / 64), 256, 0, stream>>>(
            yh, yl, woh + l * DD, wol + l * DD, nullptr, nullptr,
            x, nullptr, nullptr, BS_, D_, D_);
        ln_kernel<<<BS_ / 4, 256, 0, stream>>>(x, ln2_s + l * D_, ln2_b + l * D_, yh, yl);
        mgemm_kernel<2, 128, 128, 4, 4, true><<<dim3(MLP_ / 128, BS_ / 128), 256, 0, stream>>>(
            yh, yl, w1h + l * DM, w1l + l * DM, nullptr, b1 + (size_t)l * MLP_,
            nullptr, hbh, hbl, BS_, MLP_, D_);
        mgemm_kernel<3, 64, 64, 2, 2, true><<<dim3(D_ / 64, BS_ / 64), 256, 0, stream>>>(
            hbh, hbl, w2h + l * DM, w2l + l * DM, nullptr, b2 + (size_t)l * D_,
            x, nullptr, nullptr, BS_, D_, MLP_);
    }

    ln_kernel<<<BS_ / 4, 256, 0, stream>>>(x, lnf_s, lnf_b, yh, yl);
    mgemm_kernel<4, 128, 128, 4, 4, false><<<dim3(V_ / 128, BS_ / 128), 256, 0, stream>>>(
        yh, yl, nullptr, nullptr, w_out, b_out,
        out, nullptr, nullptr, BS_, V_, D_);
}